// Round 7
// baseline (575.329 us; speedup 1.0000x reference)
//
#include <hip/hip_runtime.h>
#include <hip/hip_bf16.h>

// Model dims: B=8, S=256, C=4, L=256, E=256, H=8, DH=32, NL=2, NS=8
// (Resubmission of round-5 kernel: bench infra failed, no counters produced.)

typedef float floatx4 __attribute__((ext_vector_type(4)));
typedef float f32x2 __attribute__((ext_vector_type(2)));
typedef short bf16x8 __attribute__((ext_vector_type(8)));

__device__ __forceinline__ float wave_sum(float v) {
    v += __shfl_xor(v, 32); v += __shfl_xor(v, 16); v += __shfl_xor(v, 8);
    v += __shfl_xor(v, 4);  v += __shfl_xor(v, 2);  v += __shfl_xor(v, 1);
    return v;
}
__device__ __forceinline__ float wave_max(float v) {
    v = fmaxf(v, __shfl_xor(v, 32)); v = fmaxf(v, __shfl_xor(v, 16));
    v = fmaxf(v, __shfl_xor(v, 8));  v = fmaxf(v, __shfl_xor(v, 4));
    v = fmaxf(v, __shfl_xor(v, 2));  v = fmaxf(v, __shfl_xor(v, 1));
    return v;
}
__device__ __forceinline__ unsigned short f2bf(float v) {
    unsigned b = __float_as_uint(v);
    unsigned r = (b + 0x7fffu + ((b >> 16) & 1u)) >> 16;
    return (unsigned short)r;
}

typedef const __attribute__((address_space(1))) unsigned int* gas_u32p;
typedef __attribute__((address_space(3))) unsigned int* las_u32p;

// Async-stage one 16KB A-chunk (already laid out + swizzled by prep) into LDS.
// Per wave: 2KB slice = 2 x global_load_lds_dwordx4 (no VGPR round-trip).
__device__ __forceinline__ void stage_chunk(const unsigned short* gbase,
                                            unsigned short* lbase,
                                            int wv, int lane)
{
    const char* g = (const char*)gbase + (wv << 11) + (lane << 4);
    char* l = (char*)lbase + (wv << 11);
    __builtin_amdgcn_global_load_lds((gas_u32p)(const void*)g,
                                     (las_u32p)(void*)l, 16, 0, 0);
    __builtin_amdgcn_global_load_lds((gas_u32p)(const void*)(g + 1024),
                                     (las_u32p)(void*)(l + 1024), 16, 0, 0);
}

// Merged prep: role by block range (all independent).
//   bid [0,2048)    : zero cnnmax / dmax; seed out with fc bias
//   bid [2048,5120) : transpose transformer weights -> bf16 Wt[n][k]
//   bid [5120,6144) : w2 -> w2b chunked+swizzled bf16, float4-coalesced reads
//                     + LDS offset table (no per-element div/mod)
// w2b layout: [256 s][12 chunk][8192]; chunk c covers kk = c*32..c*32+31
// (kk = tap*128+ci); within a chunk 16B-unit u = (kk_rel>>3) stored at
// u' = (u ^ co ^ (co>>2)) & 3 (invariant across MFMA fragment r index).
__global__ __launch_bounds__(256) void prep_all_kernel(
    unsigned* __restrict__ dmax, unsigned* __restrict__ cnnmax,
    const float* __restrict__ wq, const float* __restrict__ wk,
    const float* __restrict__ wv, const float* __restrict__ wo,
    const float* __restrict__ f1, const float* __restrict__ f2,
    unsigned short* __restrict__ wtb,
    const float* __restrict__ w2, unsigned short* __restrict__ w2b,
    const float* __restrict__ fcb, float* __restrict__ outbuf)
{
    __shared__ float t[32][33];
    __shared__ unsigned tbl[1536];
    const int bid = blockIdx.x;
    const int tid = threadIdx.x;

    if (bid < 2048) {
        const size_t i = (size_t)bid * 256 + tid;
        cnnmax[i] = 0u;
        if (i == 0) *dmax = 0u;
        if (bid == 0 && tid < 16) outbuf[tid] = fcb[tid & 1];
        return;
    }
    if (bid < 5120) {
        const int idx = bid - 2048;
        const int z = idx >> 8;             // 0..11
        const int by = (idx >> 4) & 15;
        const int bx = idx & 15;
        const int l = z / 6, id = z % 6;
        const float* src; int K_, N_; size_t doff;
        switch (id) {
            case 0:  src = wq + (size_t)l * 65536;  K_ = 256; N_ = 256; doff = 0;      break;
            case 1:  src = wk + (size_t)l * 65536;  K_ = 256; N_ = 256; doff = 65536;  break;
            case 2:  src = wv + (size_t)l * 65536;  K_ = 256; N_ = 256; doff = 131072; break;
            case 3:  src = wo + (size_t)l * 65536;  K_ = 256; N_ = 256; doff = 196608; break;
            case 4:  src = f1 + (size_t)l * 131072; K_ = 256; N_ = 512; doff = 262144; break;
            default: src = f2 + (size_t)l * 131072; K_ = 512; N_ = 256; doff = 393216; break;
        }
        const int k0 = bx * 32, n0 = by * 32;
        if (k0 >= K_ || n0 >= N_) return;
        unsigned short* dst = wtb + (size_t)l * 524288 + doff;
        const int c = tid & 31, rq = tid >> 5;
#pragma unroll
        for (int i = 0; i < 4; i++) {
            const int r = rq + i * 8;
            t[r][c] = src[(size_t)(k0 + r) * N_ + n0 + c];
        }
        __syncthreads();
#pragma unroll
        for (int i = 0; i < 4; i++) {
            const int r = rq + i * 8;
            dst[(size_t)(n0 + r) * K_ + k0 + c] = f2bf(t[c][r]);
        }
        return;
    }
    {
        const int idx = bid - 5120;         // 0..1023
        const int s = idx & 255;
        const int part = idx >> 8;          // 0..3
        // Build co-independent offset table: tbl[sw][j] for j = ci*3+tap.
        for (int i = tid; i < 1536; i += 256) {
            const int sw = i / 384, j = i - sw * 384;
            const int ci = (j * 21846) >> 16;       // j/3 exact for j<384
            const int tap = j - ci * 3;
            const int kk = tap * 128 + ci;
            const int c = kk >> 5, rel = kk & 31;
            const int u = rel >> 3, tt = rel & 7;
            tbl[i] = (unsigned)(c * 8192 + (((u ^ sw) & 3) << 3) + tt);
        }
        __syncthreads();
        const float4* src4 = (const float4*)(w2 + (size_t)s * 98304);
        unsigned short* dst = w2b + (size_t)s * 98304;
        for (int q = part * 6144 + tid; q < (part + 1) * 6144; q += 256) {
            const int co = (((q >> 5) * 21846) >> 16);   // q/96 exact
            const int j0 = (q - co * 96) * 4;
            const int sw = (co ^ (co >> 2)) & 3;
            const unsigned* tb = &tbl[sw * 384 + j0];
            const float4 v = src4[q];
            const int base = co * 32;
            dst[tb[0] + base] = f2bf(v.x);
            dst[tb[1] + base] = f2bf(v.y);
            dst[tb[2] + base] = f2bf(v.z);
            dst[tb[3] + base] = f2bf(v.w);
        }
    }
}

// Fused conv1+conv2 implicit GEMM (round-2 verified structure).
// conv1 2-co-per-thread via packed f32x2 fma (v_pk_fma_f32) — halves
// conv1's VALU instruction count; per-element fp32 math order unchanged.
// Decode: xcd = bid&7, s = xcd*32 + (pos>>4), nt = pos&15: the 16 nt-blocks
// of a segment dispatch CONSECUTIVELY on ONE XCD -> 192KB w2b slice is
// L2-resident, all stage loads are L2 hits (FETCH ~30MB verified).
// K-loop: one barrier per step, exact vmcnt(0), stage-next-chunk at step top.
__global__ __launch_bounds__(512, 4) void conv2_fused_kernel(
    const unsigned short* __restrict__ w2b,   // [256 s][12][8192] swizzled bf16
    const float* __restrict__ x,              // [8][256][4][256]
    const float* __restrict__ w1,             // [256][128][12]
    const float* __restrict__ b1,             // [256][128]
    const float* __restrict__ b2,             // [256][256]
    unsigned* __restrict__ cnnmax)            // [2048][256] f32-as-u32, relu'd
{
    __shared__ float xs[4][258];
    __shared__ float w1s[1536];
    __shared__ unsigned short Hs[130 * 136];
    __shared__ unsigned short Ab[2][8192];    // A-chunk double buffer (2x16KB)

    const int tid = threadIdx.x;
    const int lane = tid & 63;
    const int wv = __builtin_amdgcn_readfirstlane((int)(tid >> 6));
    const int wm = wv & 3, wn = wv >> 2;
    const int bid = blockIdx.x;
    const int xcd = bid & 7;
    const int pos = bid >> 3;
    const int s   = xcd * 32 + (pos >> 4);   // 0..255, one XCD per segment
    const int nt  = pos & 15;
    const int b = nt >> 1;
    const int l0 = (nt & 1) * 128;
    const int lr = lane & 15;
    const int quad = lane >> 4;
    const int qk = quad * 8;

    // ---- stage x slice + w1 slice; preload per-thread conv1 bias pair ----
    const float* xp = x + ((size_t)(b * 256 + s)) * 1024;
    for (int i = tid; i < 1024; i += 512) {
        const int ci = i >> 8, l = i & 255;
        xs[ci][l + 1] = xp[i];
    }
    if (tid < 4) { xs[tid][0] = 0.f; xs[tid][257] = 0.f; }
    const float* w1p = w1 + (size_t)s * 1536;
    for (int i = tid; i < 1536; i += 512) w1s[i] = w1p[i];
    const int co2 = (tid & 63) * 2;           // even co, thread handles (co2, co2+1)
    const f32x2 bb2 = {b1[s * 128 + co2], b1[s * 128 + co2 + 1]};
    __syncthreads();   // full drain: after this, vmcnt counts ONLY stage loads

    // ---- issue async A-stage of chunk 0; latency hides under conv1 ----
    const unsigned short* wchunks = w2b + (size_t)s * 98304;
    stage_chunk(wchunks, &Ab[0][0], wv, lane);

    // ---- conv1 phase: 130 rows x 128 co, packed 2-co per thread ----
    {
        const int g8 = tid >> 6;              // 0..7
        f32x2 wreg[12];
#pragma unroll
        for (int k = 0; k < 12; k++)
            wreg[k] = (f32x2){w1s[co2 * 12 + k], w1s[co2 * 12 + 12 + k]};
        for (int pr = g8; pr < 130; pr += 8) {
            const int l = l0 - 1 + pr;
            unsigned pk = 0u;
            if ((unsigned)l < 256u) {
                f32x2 a2 = bb2;
#pragma unroll
                for (int ci = 0; ci < 4; ci++)
#pragma unroll
                    for (int k = 0; k < 3; k++) {
                        const float xv = xs[ci][l + k];
                        a2 = __builtin_elementwise_fma(wreg[ci * 3 + k], (f32x2){xv, xv}, a2);
                    }
                a2 = __builtin_elementwise_max(a2, (f32x2){0.f, 0.f});
                pk = (unsigned)f2bf(a2.x) | ((unsigned)f2bf(a2.y) << 16);
            }
            *(unsigned*)&Hs[pr * 136 + co2] = pk;
        }
    }

    // ---- conv2 MFMA K-loop: 1 barrier/step, exact vmcnt, 1-step lookahead ----
    floatx4 acc[4][4];
#pragma unroll
    for (int r = 0; r < 4; r++)
#pragma unroll
        for (int c = 0; c < 4; c++) acc[r][c] = (floatx4){0.f, 0.f, 0.f, 0.f};

    const int nb = wn * 64;
    // A fragment base (shorts): swizzled u' is invariant across r (co += 16)
    const int aoff = wm * 2048 + lr * 32 + (((quad ^ lr ^ (lr >> 2)) & 3) * 8);
    const int hbase = (nb + lr) * 136 + qk;

    // Hs writes + chunk0 arrival, then single block-wide sync
    asm volatile("s_waitcnt vmcnt(0) lgkmcnt(0)" ::: "memory");
    __builtin_amdgcn_s_barrier();
    __builtin_amdgcn_sched_barrier(0);

#pragma unroll
    for (int ks = 0; ks < 12; ks++) {
        if (ks) {
            // chunk ks arrived (own loads; nothing younger in flight -> exact)
            asm volatile("s_waitcnt vmcnt(0)" ::: "memory");
            // all waves: chunk ks everywhere + prev step's ds_reads retired
            __builtin_amdgcn_s_barrier();
            __builtin_amdgcn_sched_barrier(0);
        }
        if (ks < 11)
            stage_chunk(wchunks + (size_t)(ks + 1) * 8192, &Ab[(ks + 1) & 1][0], wv, lane);
        const int tap_ = ks >> 2, ci0_ = (ks & 3) * 32;
        const unsigned short* ap = &Ab[ks & 1][aoff];
        const unsigned short* hp = &Hs[hbase + tap_ * 136 + ci0_];
        bf16x8 a[4], bb[4];
#pragma unroll
        for (int r = 0; r < 4; r++) a[r] = *(const bf16x8*)(ap + r * 512);
#pragma unroll
        for (int c = 0; c < 4; c++) bb[c] = *(const bf16x8*)(hp + c * 2176);
#pragma unroll
        for (int r = 0; r < 4; r++)
#pragma unroll
            for (int c = 0; c < 4; c++)
                acc[r][c] = __builtin_amdgcn_mfma_f32_16x16x32_bf16(
                    a[r], bb[c], acc[r][c], 0, 0, 0);
    }

    // ---- epilogue: bias + relu-max over L, atomicMax into cnnmax ----
    const float* b2s = b2 + s * 256;
    unsigned* cmrow = cnnmax + ((size_t)(b * 256 + s)) * 256;
#pragma unroll
    for (int r = 0; r < 4; r++) {
#pragma unroll
        for (int e = 0; e < 4; e++) {
            const int co = wm * 64 + r * 16 + quad * 4 + e;
            const float bias = b2s[co];
            float mv = 0.f;
#pragma unroll
            for (int c = 0; c < 4; c++) mv = fmaxf(mv, acc[r][c][e] + bias);
            mv = fmaxf(mv, __shfl_xor(mv, 1));
            mv = fmaxf(mv, __shfl_xor(mv, 2));
            mv = fmaxf(mv, __shfl_xor(mv, 4));
            mv = fmaxf(mv, __shfl_xor(mv, 8));
            if (lr == 0) atomicMax(&cmrow[co], __float_as_uint(mv));
        }
    }
}

// LayerNorm (no affine) from cnnmax -> feat(h); fused sum-of-squares -> sqv
__global__ __launch_bounds__(256) void ln0_kernel(
    const unsigned* __restrict__ cm, float* __restrict__ out, float* __restrict__ sqv)
{
    const int tid = threadIdx.x, lane = tid & 63, wid = tid >> 6;
    const int row = blockIdx.x * 4 + wid;
    const unsigned* xr = cm + (size_t)row * 256;
    float v[4];
#pragma unroll
    for (int i = 0; i < 4; i++) v[i] = __uint_as_float(xr[lane + 64 * i]);
    float sm = wave_sum(v[0] + v[1] + v[2] + v[3]);
    const float mean = sm * (1.f / 256.f);
    float qv = 0.f;
#pragma unroll
    for (int i = 0; i < 4; i++) { const float d = v[i] - mean; qv = fmaf(d, d, qv); }
    qv = wave_sum(qv);
    const float inv = rsqrtf(qv * (1.f / 256.f) + 1e-5f);
    float* orow = out + (size_t)row * 256;
#pragma unroll
    for (int i = 0; i < 4; i++) orow[lane + 64 * i] = (v[i] - mean) * inv;
    if (lane == 0) sqv[row] = qv * inv * inv;
}

// pairwise distances for one (b, 32-i-tile, 16-j-tile); global max via atomic
__global__ __launch_bounds__(256) void dist_kernel(
    const float* __restrict__ feat, const float* __restrict__ sq,
    float* __restrict__ dist, unsigned* __restrict__ dmax)
{
    __shared__ float Fi[32][260];
    __shared__ float Fj[16][260];
    __shared__ float redm[4];
    const int tid = threadIdx.x;
    const int bid = blockIdx.x;
    const int b = bid >> 7, it = (bid >> 4) & 7, jt = bid & 15;
    const float* fb = feat + (size_t)b * 65536;
    for (int idx = tid; idx < 32 * 256; idx += 256) {
        const int r = idx >> 8, e = idx & 255;
        Fi[r][e] = fb[(it * 32 + r) * 256 + e];
    }
    for (int idx = tid; idx < 16 * 256; idx += 256) {
        const int r = idx >> 8, e = idx & 255;
        Fj[r][e] = fb[(jt * 16 + r) * 256 + e];
    }
    __syncthreads();
    const int ii = tid >> 3, j0 = (tid & 7) * 2;
    float acc[2] = {0.f, 0.f};
    for (int e = 0; e < 256; e += 4) {
        const float4 a = *(const float4*)&Fi[ii][e];
#pragma unroll
        for (int u = 0; u < 2; u++) {
            const float4 bv = *(const float4*)&Fj[j0 + u][e];
            acc[u] += a.x * bv.x + a.y * bv.y + a.z * bv.z + a.w * bv.w;
        }
    }
    const float sqi = sq[b * 256 + it * 32 + ii];
    float mymax = 0.f;
#pragma unroll
    for (int u = 0; u < 2; u++) {
        const float d2 = sqi + sq[b * 256 + jt * 16 + j0 + u] - 2.f * acc[u];
        const float d = sqrtf(fmaxf(d2, 0.f));
        dist[((size_t)b * 256 + it * 32 + ii) * 256 + jt * 16 + j0 + u] = d;
        mymax = fmaxf(mymax, d);
    }
    mymax = wave_max(mymax);
    if ((tid & 63) == 0) redm[tid >> 6] = mymax;
    __syncthreads();
    if (tid == 0) {
        const float m = fmaxf(fmaxf(redm[0], redm[1]), fmaxf(redm[2], redm[3]));
        atomicMax(dmax, __float_as_uint(m));
    }
}

// Fused LayerNorm + bf16 MFMA GEMM: C = LN(hf) @ Wt^T (+bias, mode epilogue).
// Block 128 (2 waves), block tile 64m x 32n; grid (32, N/32). LN computed
// in-block (4 rows/pass, 16-lane groups) -> bf16 in LDS -> MFMA A-operand.
__global__ __launch_bounds__(128) void gemm_ln_kernel(
    const float* __restrict__ hf, const unsigned short* __restrict__ Wt,
    const float* __restrict__ g, const float* __restrict__ bta,
    const float* __restrict__ b0, const float* __restrict__ b1, const float* __restrict__ b2,
    unsigned short* __restrict__ o0, unsigned short* __restrict__ o1, unsigned short* __restrict__ o2,
    int mode)
{
    __shared__ unsigned short As[64 * 264];
    const int tid = threadIdx.x;
    const int lane = tid & 63, lr = lane & 15, quad = lane >> 4;
    const int wv = __builtin_amdgcn_readfirstlane((int)(tid >> 6));
    const int m0 = blockIdx.x * 64;
    const int n0 = blockIdx.y * 32;

    // ---- LN preamble: 64 rows, 4 rows/pass per wave, 16-lane groups ----
    {
        const int g16 = lane >> 4, l16 = lane & 15;
        const int c0 = l16 * 16;
        float4 g4[4], bt4[4];
#pragma unroll
        for (int k = 0; k < 4; k++) {
            g4[k]  = *(const float4*)&g[c0 + 4 * k];
            bt4[k] = *(const float4*)&bta[c0 + 4 * k];
        }
#pragma unroll
        for (int pass = 0; pass < 8; pass++) {
            const int row = wv * 32 + pass * 4 + g16;
            const float* hr = hf + (size_t)(m0 + row) * 256 + c0;
            float4 v[4];
#pragma unroll
            for (int k = 0; k < 4; k++) v[k] = *(const float4*)&hr[4 * k];
            float s = 0.f;
#pragma unroll
            for (int k = 0; k < 4; k++) s += v[k].x + v[k].y + v[k].z + v[k].w;
            s += __shfl_xor(s, 1); s += __shfl_xor(s, 2);
            s += __shfl_xor(s, 4); s += __shfl_xor(s, 8);
            const float mean = s * (1.f / 256.f);
            float q = 0.f;
#pragma unroll
            for (int k = 0; k < 4; k++) {
                float d;
                d = v[k].x - mean; q = fmaf(d, d, q);
                d = v[k].y - mean; q = fmaf(d, d, q);
                d = v[k].z - mean; q = fmaf(d, d, q);
                d = v[k].w - mean; q = fmaf(d, d, q);
            }
            q += __shfl_xor(q, 1); q += __shfl_xor(q, 2);
            q += __shfl_xor(q, 4); q += __shfl_xor(q, 8);
            const float inv = rsqrtf(q * (1.f / 256.f) + 1e-5f);
            unsigned* dst = (unsigned*)&As[row * 264 + c0];
#pragma unroll
            for (int k = 0; k < 4; k++) {
                const float f0 = (v[k].x - mean) * inv * g4[k].x + bt4[k].x;
                const float f1 = (v[k].y - mean) * inv * g4[k].y + bt4[k].y;
                const float f2 = (v[k].z - mean) * inv * g4[k].z + bt4[k].z;
                const float f3 = (v[k].w - mean) * inv * g4[k].w + bt4[k].w;
                dst[2 * k]     = (unsigned)f2bf(f0) | ((unsigned)f2bf(f1) << 16);
                dst[2 * k + 1] = (unsigned)f2bf(f2) | ((unsigned)f2bf(f3) << 16);
            }
        }
    }
    __syncthreads();

    // ---- MFMA K-loop: A from LDS, B (weights) from global (L2/L3-hot) ----
    floatx4 acc[2][2];
#pragma unroll
    for (int r = 0; r < 2; r++)
#pragma unroll
        for (int c = 0; c < 2; c++) acc[r][c] = (floatx4){0.f, 0.f, 0.f, 0.f};

    const unsigned short* Ap = &As[(wv * 32 + lr) * 264 + quad * 8];
    const unsigned short* Bp = Wt + (size_t)(n0 + lr) * 256 + quad * 8;
#pragma unroll
    for (int ks = 0; ks < 8; ks++) {
        const int ko = ks * 32;
        bf16x8 a[2], b[2];
#pragma unroll
        for (int r = 0; r < 2; r++) a[r] = *(const bf16x8*)(Ap + r * 16 * 264 + ko);
#pragma unroll
        for (int c = 0; c < 2; c++) b[c] = *(const bf16x8*)(Bp + (size_t)c * 16 * 256 + ko);
#pragma unroll
        for (int r = 0; r < 2; r++)
#pragma unroll
            for (int c = 0; c < 2; c++)
                acc[r][c] = __builtin_amdgcn_mfma_f32_16x16x32_bf16(a[r], b[c], acc[r][c], 0, 0, 0);
    }

    const int mw0 = m0 + wv * 32;
    if (mode == 0) {
        const int which = n0 >> 8, nn0 = n0 & 255;
        if (which < 2) {
            unsigned short* op = which ? o1 : o0;
            const float* bp = which ? b1 : b0;
#pragma unroll
            for (int r = 0; r < 2; r++)
#pragma unroll
                for (int c = 0; c < 2; c++)
#pragma unroll
                    for (int e = 0; e < 4; e++) {
                        const int m = mw0 + r * 16 + quad * 4 + e;
                        const int n = nn0 + c * 16 + lr;
                        op[(size_t)m * 256 + n] = f2bf(acc[r][c][e] + bp[n]);
                    }
        } else {
#pragma unroll
            for (int r = 0; r < 2; r++)
#pragma unroll
                for (int c = 0; c < 2; c++)
#pragma unroll
                    for (int e = 0; e < 4; e++) {
                        const int m = mw0 + r * 16 + quad * 4 + e;
                        const int nn = nn0 + c * 16 + lr;
                        const int bb_ = m >> 8, j = m & 255, hh = nn >> 5, d = nn & 31;
                        o2[(size_t)((bb_ * 8 + hh) * 32 + d) * 256 + j] = f2bf(acc[r][c][e] + b2[nn]);
                    }
        }
    } else {
#pragma unroll
        for (int r = 0; r < 2; r++)
#pragma unroll
            for (int c = 0; c < 2; c++)
#pragma unroll
                for (int e = 0; e < 4; e++) {
                    const int m = mw0 + r * 16 + quad * 4 + e;
                    const int n = n0 + c * 16 + lr;
                    o0[(size_t)m * 512 + n] = f2bf(fmaxf(acc[r][c][e] + b0[n], 0.f));
                }
    }
}

// bf16 MFMA GEMM: C[M=2048][N] = A[M][K] @ Wt[N][K]^T (+bias, mode epilogue)
// block 128 (2 waves stacked in m), wave tile 32m x 32n; grid (32, N/32).
__global__ __launch_bounds__(128) void gemm_mfma_kernel(
    const unsigned short* __restrict__ A, const unsigned short* __restrict__ Wt,
    const float* __restrict__ b0, const float* __restrict__ b1, const float* __restrict__ b2,
    const float* __restrict__ R, float* __restrict__ outf,
    unsigned short* __restrict__ o0, unsigned short* __restrict__ o1, unsigned short* __restrict__ o2,
    int K, int mode)
{
    const int tid = threadIdx.x;
    const int lane = tid & 63, lr = lane & 15, quad = lane >> 4;
    const int wv = __builtin_amdgcn_readfirstlane((int)(tid >> 6));
    const int m0 = blockIdx.x * 64 + wv * 32;
    const int n0 = blockIdx.y * 32;

    floatx4 acc[2][2];
#pragma unroll
    for (int r = 0; r < 2; r++)
#pragma unroll
        for (int c = 0; c < 2; c++) acc[r][c] = (floatx4){0.f, 0.f, 0.f, 0.f};

    const unsigned short* Ap = A + (size_t)(m0 + lr) * K + quad * 8;
    const unsigned short* Bp = Wt + (size_t)(n0 + lr) * K + quad * 8;
    const int nks = K >> 5;
#pragma unroll 4
    for (int ks = 0; ks < nks; ks++) {
        const int ko = ks * 32;
        bf16x8 a[2], b[2];
#pragma unroll
        for (int r = 0; r < 2; r++) a[r] = *(const bf16x8*)(Ap + (size_t)r * 16 * K + ko);
#pragma unroll
        for (int c = 0; c < 2; c++) b[c] = *(const bf16x8*)(Bp + (size_t)c * 16 * K + ko);
#pragma unroll
        for (int r = 0; r < 2; r++)
#pragma unroll
            for (int c = 0; c < 2; c++)
                acc[r][c] = __builtin_amdgcn_mfma_f32_16x16x32_bf16(a[r], b[c], acc[r][c], 0, 0, 0);
    }

    if (mode == 0) {
        const int which = n0 >> 8, nn0 = n0 & 255;
        if (which < 2) {
            unsigned short* op = which ? o1 : o0;
            const float* bp = which ? b1 : b0;
#pragma unroll
            for (int r = 0; r < 2; r++)
#pragma unroll
                for (int c = 0; c < 2; c++)
#pragma unroll
                    for (int e = 0; e < 4; e++) {
                        const int m = m0 + r * 16 + quad * 4 + e;
                        const int n = nn0 + c * 16 + lr;
                        op[(size_t)m * 256 + n] = f2bf(acc[r][c][e] + bp[n]);
                    }
        } else {
#pragma unroll
            for (int r = 0; r < 2; r++)
#pragma unroll
                for (int c = 0; c < 2; c++)
#pragma unroll
                    for (int e = 0; e < 4; e++) {
                        const int m = m0 + r * 16 + quad * 4 + e;
                        const int nn = nn0 + c * 16 + lr;
                        const int bb_ = m >> 8, j = m & 255, hh = nn >> 5, d = nn & 31;
                        o2[(size_t)((bb_ * 8 + hh) * 32 + d) * 256 + j] = f2bf(acc[r][c][e] + b2[nn]);
                    }
        }
    } else if (mode == 1) {
#pragma unroll
        for (int r = 0; r < 2; r++)
#pragma unroll
            for (int c = 0; c < 2; c++)
#pragma unroll
                for (int e = 0; e < 4; e++) {
                    const int m = m0 + r * 16 + quad * 4 + e;
                    const int n = n0 + c * 16 + lr;
                    outf[(size_t)m * 256 + n] = acc[r][c][e] + b0[n] + R[(size_t)m * 256 + n];
                }
    } else {
#pragma unroll
        for (int r = 0; r < 2; r++)
#pragma unroll
            for (int c = 0; c < 2; c++)
#pragma unroll
                for (int e = 0; e < 4; e++) {
                    const int m = m0 + r * 16 + quad * 4 + e;
                    const int n = n0 + c * 16 + lr;
                    o0[(size_t)m * 512 + n] = f2bf(fmaxf(acc[r][c][e] + b0[n], 0.f));
                }
    }
}

// MFMA attention: grid (4 ic, 8 h, 8 b), block 256 (4 waves, wave = one 16-i tile)
__global__ __launch_bounds__(256) void attn_mfma_kernel(
    const unsigned short* __restrict__ q_bf, const unsigned short* __restrict__ k_bf,
    const unsigned short* __restrict__ vt_bf,
    const float* __restrict__ dist, const unsigned* __restrict__ dmax,
    const float* __restrict__ bw, const float* __restrict__ bb,
    unsigned short* __restrict__ ao_bf)
{
    __shared__ unsigned short Ps[4][16][264];
    const int tid = threadIdx.x;
    const int lane = tid & 63, lr = lane & 15, quad = lane >> 4;
    const int wv = __builtin_amdgcn_readfirstlane((int)(tid >> 6));
    const int ic = blockIdx.x, hh = blockIdx.y, b = blockIdx.z;
    const int i0 = ic * 64 + wv * 16;

    const float dinv = 1.f / (__uint_as_float(*dmax) + 1e-6f);
    const float w0 = bw[0 * 8 + hh], w1 = bw[1 * 8 + hh], w2 = bw[2 * 8 + hh], w3 = bw[3 * 8 + hh];
    const float bbh = bb[hh];
    const float scale = 0.17677669529663687f;

    const bf16x8 aq = *(const bf16x8*)(q_bf + (size_t)(b * 256 + i0 + lr) * 256 + hh * 32 + quad * 8);
    floatx4 sc[16];
#pragma unroll
    for (int c = 0; c < 16; c++) {
        const bf16x8 bk = *(const bf16x8*)(k_bf + (size_t)(b * 256 + c * 16 + lr) * 256 + hh * 32 + quad * 8);
        sc[c] = __builtin_amdgcn_mfma_f32_16x16x32_bf16(aq, bk, (floatx4){0.f, 0.f, 0.f, 0.f}, 0, 0, 0);
    }

#pragma unroll
    for (int e = 0; e < 4; e++) {
        const int i = i0 + quad * 4 + e;
        const float* drow = dist + ((size_t)(b * 256 + i)) * 256;
        float bs[16];
        float mx = -1e30f;
#pragma unroll
        for (int c = 0; c < 16; c++) {
            const int j = c * 16 + lr;
            const float dn = drow[j] * dinv;
            const float rd = fabsf((float)(i - j)) * (1.f / 255.f);
            bs[c] = sc[c][e] * scale + w0 * dn + w1 * rd + w2 * (1.f - rd) + w3 * (1.f - dn) + bbh;
            mx = fmaxf(mx, bs[c]);
        }
        mx = fmaxf(mx, __shfl_xor(mx, 1)); mx = fmaxf(mx, __shfl_xor(mx, 2));
        mx = fmaxf(mx, __shfl_xor(mx, 4)); mx = fmaxf(mx, __shfl_xor(mx, 8));
        float sm = 0.f;
#pragma unroll
        for (int c = 0; c < 16; c++) { bs[c] = __expf(bs[c] - mx); sm += bs[c]; }
        sm += __shfl_xor(sm, 1); sm += __shfl_xor(sm, 2);
        sm += __shfl_xor(sm, 4); sm += __shfl_xor(sm, 8);
        const float rs = 1.f / sm;
#pragma unroll
        for (int c = 0; c < 16; c++)
            Ps[wv][quad * 4 + e][c * 16 + lr] = f2bf(bs[c] * rs);
    }
    __syncthreads();

    floatx4 oc[2];
    oc[0] = (floatx4){0.f, 0.f, 0.f, 0.f};
    oc[1] = (floatx4){0.f, 0.f, 0.f, 0.f};
    const unsigned short* vtb = vt_bf + (size_t)(b * 8 + hh) * 8192;
#pragma unroll
    for (int ks = 0; ks < 8; ks++) {
        const bf16x8 ap = *(const bf16x8*)(&Ps[wv][lr][ks * 32 + quad * 8]);
#pragma unroll
        for (int c2 = 0; c2 < 2; c2++) {
            const bf16x8 bvv = *(const bf16x8*)(vtb + (size_t)(c2 * 16 + lr) * 256 + ks * 32 + quad * 8);
            oc[c2] = __builtin_amdgcn_mfma_f32_16x16x32_bf16(ap, bvv, oc[c2], 0, 0, 0);
        }
    }
#pragma unroll
    for (int c2 = 0; c2 < 2; c2++)
#pragma unroll
        for (int e = 0; e < 4; e++)
            ao_bf[(size_t)(b * 256 + i0 + quad * 4 + e) * 256 + hh * 32 + c2 * 16 + lr] = f2bf(oc[c2][e]);
}

// chunked max-pool over segments + final FC, spread over (b, ns) = 64 blocks;
// partial dot products atomicAdd'ed into out (bias pre-seeded by prep_all).
__global__ __launch_bounds__(256) void pool_fc_kernel(
    const float* __restrict__ h, const float* __restrict__ fcw,
    float* __restrict__ out)
{
    __shared__ float red[8];
    const int b = blockIdx.x, ns = blockIdx.y;
    const int tid = threadIdx.x, lane = tid & 63, wid = tid >> 6;
    const float* hp = h + ((size_t)(b * 256 + ns * 32)) * 256 + tid;
    float m = hp[0];
#pragma unroll
    for (int r = 1; r < 32; r++) m = fmaxf(m, hp[(size_t)r * 256]);
    float a0 = m * fcw[(ns * 256 + tid) * 2 + 0];
    float a1 = m * fcw[(ns * 256 + tid) * 2 + 1];
    a0 = wave_sum(a0);
    a1 = wave_sum(a1);
    if (lane == 0) { red[wid] = a0; red[4 + wid] = a1; }
    __syncthreads();
    if (tid == 0) atomicAdd(&out[b * 2 + 0], red[0] + red[1] + red[2] + red[3]);
    if (tid == 1) atomicAdd(&out[b * 2 + 1], red[4] + red[5] + red[6] + red[7]);
}

extern "C" void kernel_launch(void* const* d_in, const int* in_sizes, int n_in,
                              void* d_out, int out_size, void* d_ws, size_t ws_size,
                              hipStream_t stream)
{
    (void)in_sizes; (void)n_in; (void)out_size; (void)ws_size;
    const float* x       = (const float*)d_in[0];
    const float* conv1_w = (const float*)d_in[1];
    const float* conv1_b = (const float*)d_in[2];
    const float* conv2_w = (const float*)d_in[3];
    const float* conv2_b = (const float*)d_in[4];
    const float* ln1_g   = (const float*)d_in[5];
    const float* ln1_b   = (const float*)d_in[6];
    const float* wq = (const float*)d_in[7];  const float* bq = (const float*)d_in[8];
    const float* wk = (const float*)d_in[9];  const float* bk = (const float*)d_in[10];
    const float* wvp = (const float*)d_in[11]; const float* bv = (const float*)d_in[12];
    const float* wo = (const float*)d_in[13]; const float* bo = (const float*)d_in[14];
    const float* bias_w = (const float*)d_in[15];
    const float* bias_b = (const float*)d_in[16];
    const float* ln2_g  = (const float*)d_in[17];
    const float* ln2_b  = (const float*)d_in[18];
    const float* ffn_w1 = (const float*)d_in[19]; const float* ffn_b1 = (const float*)d_in[20];
    const float* ffn_w2 = (const float*)d_in[21]; const float* ffn_b2 = (const float*)d_in[22];
    const float* fc_w   = (const float*)d_in[23]; const float* fc_b = (const float*)d_in[24];
    float* out = (float*)d_out;

    float* ws = (float*)d_ws;
    float* h    = ws;                         // [2048,256] fp32
    float* dist = h + 524288;                 // [8,256,256] fp32
    float* sqv  = dist + 524288;              // [2048]
    unsigned* dmax = (unsigned*)(sqv + 2048);
    unsigned* cnnmax = (unsigned*)(sqv + 2048 + 16);              // [2048,256]
    unsigned short* hn_bf = (unsigned short*)(sqv + 2048 + 16 + 524288);  // [2048,256] (unused)
    unsigned short* q_bf  = hn_bf + 524288;
    unsigned short* k_bf  = q_bf + 524288;
    unsigned short* vt_bf = k_bf + 524288;    // [8,8,32,256] = [b,h,d,j]
    unsigned short* ao_bf = vt_bf + 524288;   // [2048,256]
    unsigned short* fm_bf = ao_bf + 524288;   // [2048,512]
    unsigned short* wtb   = fm_bf + 1048576;  // [2][524288]
    unsigned short* w2b   = wtb + 1048576;    // 256*12*8192 bf16 = 50.3 MB

    prep_all_kernel<<<6144, 256, 0, stream>>>(
        dmax, cnnmax, wq, wk, wvp, wo, ffn_w1, ffn_w2, wtb, conv2_w, w2b,
        fc_b, out);
    conv2_fused_kernel<<<4096, 512, 0, stream>>>(
        w2b, x, conv1_w, conv1_b, conv2_b, cnnmax);
    ln0_kernel<<<512, 256, 0, stream>>>(cnnmax, h, sqv);
    dist_kernel<<<1024, 256, 0, stream>>>(h, sqv, dist, dmax);

    for (int l = 0; l < 2; l++) {
        const unsigned short* wqkvT = wtb + (size_t)l * 524288;
        const unsigned short* woT   = wqkvT + 196608;
        const unsigned short* f1T   = wqkvT + 262144;
        const unsigned short* f2T   = wqkvT + 393216;

        gemm_ln_kernel<<<dim3(32, 24), 128, 0, stream>>>(
            h, wqkvT, ln1_g + l * 256, ln1_b + l * 256,
            bq + l * 256, bk + l * 256, bv + l * 256,
            q_bf, k_bf, vt_bf, 0);
        attn_mfma_kernel<<<dim3(4, 8, 8), 256, 0, stream>>>(
            q_bf, k_bf, vt_bf, dist, dmax, bias_w + l * 32, bias_b + l * 8, ao_bf);
        gemm_mfma_kernel<<<dim3(32, 8), 128, 0, stream>>>(
            ao_bf, woT, bo + l * 256, nullptr, nullptr,
            h, h, nullptr, nullptr, nullptr, 256, 1);
        gemm_ln_kernel<<<dim3(32, 16), 128, 0, stream>>>(
            h, f1T, ln2_g + l * 256, ln2_b + l * 256,
            ffn_b1 + l * 512, nullptr, nullptr,
            fm_bf, nullptr, nullptr, 2);
        gemm_mfma_kernel<<<dim3(32, 8), 128, 0, stream>>>(
            fm_bf, f2T, ffn_b2 + l * 256, nullptr, nullptr,
            h, h, nullptr, nullptr, nullptr, 512, 1);
    }
    pool_fc_kernel<<<dim3(8, 8), 256, 0, stream>>>(h, fc_w, out);
}

// Round 8
// 539.254 us; speedup vs baseline: 1.0669x; 1.0669x over previous
//
#include <hip/hip_runtime.h>
#include <hip/hip_bf16.h>

// Model dims: B=8, S=256, C=4, L=256, E=256, H=8, DH=32, NL=2, NS=8

typedef float floatx4 __attribute__((ext_vector_type(4)));
typedef float f32x2 __attribute__((ext_vector_type(2)));
typedef short bf16x8 __attribute__((ext_vector_type(8)));

__device__ __forceinline__ float wave_sum(float v) {
    v += __shfl_xor(v, 32); v += __shfl_xor(v, 16); v += __shfl_xor(v, 8);
    v += __shfl_xor(v, 4);  v += __shfl_xor(v, 2);  v += __shfl_xor(v, 1);
    return v;
}
__device__ __forceinline__ float wave_max(float v) {
    v = fmaxf(v, __shfl_xor(v, 32)); v = fmaxf(v, __shfl_xor(v, 16));
    v = fmaxf(v, __shfl_xor(v, 8));  v = fmaxf(v, __shfl_xor(v, 4));
    v = fmaxf(v, __shfl_xor(v, 2));  v = fmaxf(v, __shfl_xor(v, 1));
    return v;
}
__device__ __forceinline__ unsigned short f2bf(float v) {
    unsigned b = __float_as_uint(v);
    unsigned r = (b + 0x7fffu + ((b >> 16) & 1u)) >> 16;
    return (unsigned short)r;
}
// RNE pack of two finite f32 -> packed bf16x2 in one VALU op (same rounding
// as f2bf for finite inputs; used only on post-relu / LN outputs).
__device__ __forceinline__ unsigned cvt_pk_bf16(float lo, float hi) {
    unsigned r;
    asm("v_cvt_pk_bf16_f32 %0, %1, %2" : "=v"(r) : "v"(lo), "v"(hi));
    return r;
}

typedef const __attribute__((address_space(1))) unsigned int* gas_u32p;
typedef __attribute__((address_space(3))) unsigned int* las_u32p;

// Async-stage one 16KB A-chunk (already laid out + swizzled by prep) into LDS.
// Per wave: 2KB slice = 2 x global_load_lds_dwordx4 (no VGPR round-trip).
__device__ __forceinline__ void stage_chunk(const unsigned short* gbase,
                                            unsigned short* lbase,
                                            int wv, int lane)
{
    const char* g = (const char*)gbase + (wv << 11) + (lane << 4);
    char* l = (char*)lbase + (wv << 11);
    __builtin_amdgcn_global_load_lds((gas_u32p)(const void*)g,
                                     (las_u32p)(void*)l, 16, 0, 0);
    __builtin_amdgcn_global_load_lds((gas_u32p)(const void*)(g + 1024),
                                     (las_u32p)(void*)(l + 1024), 16, 0, 0);
}

// Merged prep: role by block range (all independent).
//   bid [0,2048)    : zero cnnmax / dmax; seed out with fc bias
//   bid [2048,5120) : transpose transformer weights -> bf16 Wt[n][k]
//   bid [5120,6144) : w2 -> w2b chunked+swizzled bf16 — COALESCED WRITES
//                     (round-4 pattern; the table/scatter-write version
//                     regressed ~20us: 2-byte scatter across 24KB kills
//                     write combining)
// w2b layout: [256 s][12 chunk][8192]; chunk c covers kk = c*32..c*32+31
// (kk = tap*128+ci); within a chunk 16B-unit u = (kk_rel>>3) stored at
// u' = (u ^ co ^ (co>>2)) & 3 (invariant across MFMA fragment r index).
__global__ __launch_bounds__(256) void prep_all_kernel(
    unsigned* __restrict__ dmax, unsigned* __restrict__ cnnmax,
    const float* __restrict__ wq, const float* __restrict__ wk,
    const float* __restrict__ wv, const float* __restrict__ wo,
    const float* __restrict__ f1, const float* __restrict__ f2,
    unsigned short* __restrict__ wtb,
    const float* __restrict__ w2, unsigned short* __restrict__ w2b,
    const float* __restrict__ fcb, float* __restrict__ outbuf)
{
    __shared__ float t[32][33];
    const int bid = blockIdx.x;
    const int tid = threadIdx.x;

    if (bid < 2048) {
        const size_t i = (size_t)bid * 256 + tid;
        cnnmax[i] = 0u;
        if (i == 0) *dmax = 0u;
        if (bid == 0 && tid < 16) outbuf[tid] = fcb[tid & 1];
        return;
    }
    if (bid < 5120) {
        const int idx = bid - 2048;
        const int z = idx >> 8;             // 0..11
        const int by = (idx >> 4) & 15;
        const int bx = idx & 15;
        const int l = z / 6, id = z % 6;
        const float* src; int K_, N_; size_t doff;
        switch (id) {
            case 0:  src = wq + (size_t)l * 65536;  K_ = 256; N_ = 256; doff = 0;      break;
            case 1:  src = wk + (size_t)l * 65536;  K_ = 256; N_ = 256; doff = 65536;  break;
            case 2:  src = wv + (size_t)l * 65536;  K_ = 256; N_ = 256; doff = 131072; break;
            case 3:  src = wo + (size_t)l * 65536;  K_ = 256; N_ = 256; doff = 196608; break;
            case 4:  src = f1 + (size_t)l * 131072; K_ = 256; N_ = 512; doff = 262144; break;
            default: src = f2 + (size_t)l * 131072; K_ = 512; N_ = 256; doff = 393216; break;
        }
        const int k0 = bx * 32, n0 = by * 32;
        if (k0 >= K_ || n0 >= N_) return;
        unsigned short* dst = wtb + (size_t)l * 524288 + doff;
        const int c = tid & 31, rq = tid >> 5;
#pragma unroll
        for (int i = 0; i < 4; i++) {
            const int r = rq + i * 8;
            t[r][c] = src[(size_t)(k0 + r) * N_ + n0 + c];
        }
        __syncthreads();
#pragma unroll
        for (int i = 0; i < 4; i++) {
            const int r = rq + i * 8;
            dst[(size_t)(n0 + r) * K_ + k0 + c] = f2bf(t[c][r]);
        }
        return;
    }
    {
        const int idx = bid - 5120;         // 0..1023
        const int s = idx & 255;
        const int part = idx >> 8;          // 0..3
        const float* src = w2 + (size_t)s * 98304;
        unsigned short* dst = w2b + (size_t)s * 98304;
        for (int o = part * 24576 + tid; o < (part + 1) * 24576; o += 256) {
            const int c  = o >> 13;           // chunk 0..11
            const int w  = o & 8191;
            const int co = w >> 5;            // 0..255
            const int up = (w >> 3) & 3;      // stored u'
            const int tt = w & 7;
            const int u  = (up ^ co ^ (co >> 2)) & 3;   // XOR involution
            const int kk = c * 32 + u * 8 + tt;
            const int ci = kk & 127, tap = kk >> 7;
            dst[o] = f2bf(src[(size_t)co * 384 + ci * 3 + tap]);
        }
    }
}

// Fused conv1+conv2 implicit GEMM (round-2 verified structure).
// conv1 2-co-per-thread via packed f32x2 fma + v_cvt_pk_bf16_f32 pack.
// Decode: xcd = bid&7, s = xcd*32 + (pos>>4), nt = pos&15: the 16 nt-blocks
// of a segment dispatch CONSECUTIVELY on ONE XCD -> 192KB w2b slice is
// L2-resident, all stage loads are L2 hits (FETCH ~30MB verified).
// K-loop: one barrier per step, exact vmcnt(0), stage-next-chunk at step top.
__global__ __launch_bounds__(512, 4) void conv2_fused_kernel(
    const unsigned short* __restrict__ w2b,   // [256 s][12][8192] swizzled bf16
    const float* __restrict__ x,              // [8][256][4][256]
    const float* __restrict__ w1,             // [256][128][12]
    const float* __restrict__ b1,             // [256][128]
    const float* __restrict__ b2,             // [256][256]
    unsigned* __restrict__ cnnmax)            // [2048][256] f32-as-u32, relu'd
{
    __shared__ float xs[4][258];
    __shared__ float w1s[1536];
    __shared__ unsigned short Hs[130 * 136];
    __shared__ unsigned short Ab[2][8192];    // A-chunk double buffer (2x16KB)

    const int tid = threadIdx.x;
    const int lane = tid & 63;
    const int wv = __builtin_amdgcn_readfirstlane((int)(tid >> 6));
    const int wm = wv & 3, wn = wv >> 2;
    const int bid = blockIdx.x;
    const int xcd = bid & 7;
    const int pos = bid >> 3;
    const int s   = xcd * 32 + (pos >> 4);   // 0..255, one XCD per segment
    const int nt  = pos & 15;
    const int b = nt >> 1;
    const int l0 = (nt & 1) * 128;
    const int lr = lane & 15;
    const int quad = lane >> 4;
    const int qk = quad * 8;

    // ---- stage x slice + w1 slice; preload per-thread conv1 bias pair ----
    const float* xp = x + ((size_t)(b * 256 + s)) * 1024;
    for (int i = tid; i < 1024; i += 512) {
        const int ci = i >> 8, l = i & 255;
        xs[ci][l + 1] = xp[i];
    }
    if (tid < 4) { xs[tid][0] = 0.f; xs[tid][257] = 0.f; }
    const float* w1p = w1 + (size_t)s * 1536;
    for (int i = tid; i < 1536; i += 512) w1s[i] = w1p[i];
    const int co2 = (tid & 63) * 2;           // even co, thread handles (co2, co2+1)
    const f32x2 bb2 = {b1[s * 128 + co2], b1[s * 128 + co2 + 1]};
    __syncthreads();   // full drain: after this, vmcnt counts ONLY stage loads

    // ---- issue async A-stage of chunk 0; latency hides under conv1 ----
    const unsigned short* wchunks = w2b + (size_t)s * 98304;
    stage_chunk(wchunks, &Ab[0][0], wv, lane);

    // ---- conv1 phase: 130 rows x 128 co, packed 2-co per thread ----
    {
        const int g8 = tid >> 6;              // 0..7
        f32x2 wreg[12];
#pragma unroll
        for (int k = 0; k < 12; k++)
            wreg[k] = (f32x2){w1s[co2 * 12 + k], w1s[co2 * 12 + 12 + k]};
        for (int pr = g8; pr < 130; pr += 8) {
            const int l = l0 - 1 + pr;
            unsigned pk = 0u;
            if ((unsigned)l < 256u) {
                f32x2 a2 = bb2;
#pragma unroll
                for (int ci = 0; ci < 4; ci++)
#pragma unroll
                    for (int k = 0; k < 3; k++) {
                        const float xv = xs[ci][l + k];
                        a2 = __builtin_elementwise_fma(wreg[ci * 3 + k], (f32x2){xv, xv}, a2);
                    }
                a2 = __builtin_elementwise_max(a2, (f32x2){0.f, 0.f});
                pk = cvt_pk_bf16(a2.x, a2.y);
            }
            *(unsigned*)&Hs[pr * 136 + co2] = pk;
        }
    }

    // ---- conv2 MFMA K-loop: 1 barrier/step, exact vmcnt, 1-step lookahead ----
    floatx4 acc[4][4];
#pragma unroll
    for (int r = 0; r < 4; r++)
#pragma unroll
        for (int c = 0; c < 4; c++) acc[r][c] = (floatx4){0.f, 0.f, 0.f, 0.f};

    const int nb = wn * 64;
    // A fragment base (shorts): swizzled u' is invariant across r (co += 16)
    const int aoff = wm * 2048 + lr * 32 + (((quad ^ lr ^ (lr >> 2)) & 3) * 8);
    const int hbase = (nb + lr) * 136 + qk;

    // Hs writes + chunk0 arrival, then single block-wide sync
    asm volatile("s_waitcnt vmcnt(0) lgkmcnt(0)" ::: "memory");
    __builtin_amdgcn_s_barrier();
    __builtin_amdgcn_sched_barrier(0);

#pragma unroll
    for (int ks = 0; ks < 12; ks++) {
        if (ks) {
            // chunk ks arrived (own loads; nothing younger in flight -> exact)
            asm volatile("s_waitcnt vmcnt(0)" ::: "memory");
            // all waves: chunk ks everywhere + prev step's ds_reads retired
            __builtin_amdgcn_s_barrier();
            __builtin_amdgcn_sched_barrier(0);
        }
        if (ks < 11)
            stage_chunk(wchunks + (size_t)(ks + 1) * 8192, &Ab[(ks + 1) & 1][0], wv, lane);
        const int tap_ = ks >> 2, ci0_ = (ks & 3) * 32;
        const unsigned short* ap = &Ab[ks & 1][aoff];
        const unsigned short* hp = &Hs[hbase + tap_ * 136 + ci0_];
        bf16x8 a[4], bb[4];
#pragma unroll
        for (int r = 0; r < 4; r++) a[r] = *(const bf16x8*)(ap + r * 512);
#pragma unroll
        for (int c = 0; c < 4; c++) bb[c] = *(const bf16x8*)(hp + c * 2176);
#pragma unroll
        for (int r = 0; r < 4; r++)
#pragma unroll
            for (int c = 0; c < 4; c++)
                acc[r][c] = __builtin_amdgcn_mfma_f32_16x16x32_bf16(
                    a[r], bb[c], acc[r][c], 0, 0, 0);
    }

    // ---- epilogue: bias + relu-max over L, atomicMax into cnnmax ----
    const float* b2s = b2 + s * 256;
    unsigned* cmrow = cnnmax + ((size_t)(b * 256 + s)) * 256;
#pragma unroll
    for (int r = 0; r < 4; r++) {
#pragma unroll
        for (int e = 0; e < 4; e++) {
            const int co = wm * 64 + r * 16 + quad * 4 + e;
            const float bias = b2s[co];
            float mv = 0.f;
#pragma unroll
            for (int c = 0; c < 4; c++) mv = fmaxf(mv, acc[r][c][e] + bias);
            mv = fmaxf(mv, __shfl_xor(mv, 1));
            mv = fmaxf(mv, __shfl_xor(mv, 2));
            mv = fmaxf(mv, __shfl_xor(mv, 4));
            mv = fmaxf(mv, __shfl_xor(mv, 8));
            if (lr == 0) atomicMax(&cmrow[co], __float_as_uint(mv));
        }
    }
}

// LayerNorm (no affine) from cnnmax -> feat(h); fused sum-of-squares -> sqv
__global__ __launch_bounds__(256) void ln0_kernel(
    const unsigned* __restrict__ cm, float* __restrict__ out, float* __restrict__ sqv)
{
    const int tid = threadIdx.x, lane = tid & 63, wid = tid >> 6;
    const int row = blockIdx.x * 4 + wid;
    const unsigned* xr = cm + (size_t)row * 256;
    float v[4];
#pragma unroll
    for (int i = 0; i < 4; i++) v[i] = __uint_as_float(xr[lane + 64 * i]);
    float sm = wave_sum(v[0] + v[1] + v[2] + v[3]);
    const float mean = sm * (1.f / 256.f);
    float qv = 0.f;
#pragma unroll
    for (int i = 0; i < 4; i++) { const float d = v[i] - mean; qv = fmaf(d, d, qv); }
    qv = wave_sum(qv);
    const float inv = rsqrtf(qv * (1.f / 256.f) + 1e-5f);
    float* orow = out + (size_t)row * 256;
#pragma unroll
    for (int i = 0; i < 4; i++) orow[lane + 64 * i] = (v[i] - mean) * inv;
    if (lane == 0) sqv[row] = qv * inv * inv;
}

// pairwise distances for one (b, 32-i-tile, 16-j-tile); global max via atomic
__global__ __launch_bounds__(256) void dist_kernel(
    const float* __restrict__ feat, const float* __restrict__ sq,
    float* __restrict__ dist, unsigned* __restrict__ dmax)
{
    __shared__ float Fi[32][260];
    __shared__ float Fj[16][260];
    __shared__ float redm[4];
    const int tid = threadIdx.x;
    const int bid = blockIdx.x;
    const int b = bid >> 7, it = (bid >> 4) & 7, jt = bid & 15;
    const float* fb = feat + (size_t)b * 65536;
    for (int idx = tid; idx < 32 * 256; idx += 256) {
        const int r = idx >> 8, e = idx & 255;
        Fi[r][e] = fb[(it * 32 + r) * 256 + e];
    }
    for (int idx = tid; idx < 16 * 256; idx += 256) {
        const int r = idx >> 8, e = idx & 255;
        Fj[r][e] = fb[(jt * 16 + r) * 256 + e];
    }
    __syncthreads();
    const int ii = tid >> 3, j0 = (tid & 7) * 2;
    float acc[2] = {0.f, 0.f};
    for (int e = 0; e < 256; e += 4) {
        const float4 a = *(const float4*)&Fi[ii][e];
#pragma unroll
        for (int u = 0; u < 2; u++) {
            const float4 bv = *(const float4*)&Fj[j0 + u][e];
            acc[u] += a.x * bv.x + a.y * bv.y + a.z * bv.z + a.w * bv.w;
        }
    }
    const float sqi = sq[b * 256 + it * 32 + ii];
    float mymax = 0.f;
#pragma unroll
    for (int u = 0; u < 2; u++) {
        const float d2 = sqi + sq[b * 256 + jt * 16 + j0 + u] - 2.f * acc[u];
        const float d = sqrtf(fmaxf(d2, 0.f));
        dist[((size_t)b * 256 + it * 32 + ii) * 256 + jt * 16 + j0 + u] = d;
        mymax = fmaxf(mymax, d);
    }
    mymax = wave_max(mymax);
    if ((tid & 63) == 0) redm[tid >> 6] = mymax;
    __syncthreads();
    if (tid == 0) {
        const float m = fmaxf(fmaxf(redm[0], redm[1]), fmaxf(redm[2], redm[3]));
        atomicMax(dmax, __float_as_uint(m));
    }
}

// Fused LayerNorm + bf16 MFMA GEMM: C = LN(hf) @ Wt^T (+bias, mode epilogue).
// Block 128 (2 waves), block tile 64m x 32n; grid (32, N/32). LN computed
// in-block (4 rows/pass, 16-lane groups) -> bf16 in LDS -> MFMA A-operand.
__global__ __launch_bounds__(128) void gemm_ln_kernel(
    const float* __restrict__ hf, const unsigned short* __restrict__ Wt,
    const float* __restrict__ g, const float* __restrict__ bta,
    const float* __restrict__ b0, const float* __restrict__ b1, const float* __restrict__ b2,
    unsigned short* __restrict__ o0, unsigned short* __restrict__ o1, unsigned short* __restrict__ o2,
    int mode)
{
    __shared__ unsigned short As[64 * 264];
    const int tid = threadIdx.x;
    const int lane = tid & 63, lr = lane & 15, quad = lane >> 4;
    const int wv = __builtin_amdgcn_readfirstlane((int)(tid >> 6));
    const int m0 = blockIdx.x * 64;
    const int n0 = blockIdx.y * 32;

    // ---- LN preamble: 64 rows, 4 rows/pass per wave, 16-lane groups ----
    {
        const int g16 = lane >> 4, l16 = lane & 15;
        const int c0 = l16 * 16;
        float4 g4[4], bt4[4];
#pragma unroll
        for (int k = 0; k < 4; k++) {
            g4[k]  = *(const float4*)&g[c0 + 4 * k];
            bt4[k] = *(const float4*)&bta[c0 + 4 * k];
        }
#pragma unroll
        for (int pass = 0; pass < 8; pass++) {
            const int row = wv * 32 + pass * 4 + g16;
            const float* hr = hf + (size_t)(m0 + row) * 256 + c0;
            float4 v[4];
#pragma unroll
            for (int k = 0; k < 4; k++) v[k] = *(const float4*)&hr[4 * k];
            float s = 0.f;
#pragma unroll
            for (int k = 0; k < 4; k++) s += v[k].x + v[k].y + v[k].z + v[k].w;
            s += __shfl_xor(s, 1); s += __shfl_xor(s, 2);
            s += __shfl_xor(s, 4); s += __shfl_xor(s, 8);
            const float mean = s * (1.f / 256.f);
            float q = 0.f;
#pragma unroll
            for (int k = 0; k < 4; k++) {
                float d;
                d = v[k].x - mean; q = fmaf(d, d, q);
                d = v[k].y - mean; q = fmaf(d, d, q);
                d = v[k].z - mean; q = fmaf(d, d, q);
                d = v[k].w - mean; q = fmaf(d, d, q);
            }
            q += __shfl_xor(q, 1); q += __shfl_xor(q, 2);
            q += __shfl_xor(q, 4); q += __shfl_xor(q, 8);
            const float inv = rsqrtf(q * (1.f / 256.f) + 1e-5f);
            unsigned* dst = (unsigned*)&As[row * 264 + c0];
#pragma unroll
            for (int k = 0; k < 4; k++) {
                const float f0 = (v[k].x - mean) * inv * g4[k].x + bt4[k].x;
                const float f1 = (v[k].y - mean) * inv * g4[k].y + bt4[k].y;
                const float f2 = (v[k].z - mean) * inv * g4[k].z + bt4[k].z;
                const float f3 = (v[k].w - mean) * inv * g4[k].w + bt4[k].w;
                dst[2 * k]     = cvt_pk_bf16(f0, f1);
                dst[2 * k + 1] = cvt_pk_bf16(f2, f3);
            }
        }
    }
    __syncthreads();

    // ---- MFMA K-loop: A from LDS, B (weights) from global (L2/L3-hot) ----
    floatx4 acc[2][2];
#pragma unroll
    for (int r = 0; r < 2; r++)
#pragma unroll
        for (int c = 0; c < 2; c++) acc[r][c] = (floatx4){0.f, 0.f, 0.f, 0.f};

    const unsigned short* Ap = &As[(wv * 32 + lr) * 264 + quad * 8];
    const unsigned short* Bp = Wt + (size_t)(n0 + lr) * 256 + quad * 8;
#pragma unroll
    for (int ks = 0; ks < 8; ks++) {
        const int ko = ks * 32;
        bf16x8 a[2], b[2];
#pragma unroll
        for (int r = 0; r < 2; r++) a[r] = *(const bf16x8*)(Ap + r * 16 * 264 + ko);
#pragma unroll
        for (int c = 0; c < 2; c++) b[c] = *(const bf16x8*)(Bp + (size_t)c * 16 * 256 + ko);
#pragma unroll
        for (int r = 0; r < 2; r++)
#pragma unroll
            for (int c = 0; c < 2; c++)
                acc[r][c] = __builtin_amdgcn_mfma_f32_16x16x32_bf16(a[r], b[c], acc[r][c], 0, 0, 0);
    }

    const int mw0 = m0 + wv * 32;
    if (mode == 0) {
        const int which = n0 >> 8, nn0 = n0 & 255;
        if (which < 2) {
            unsigned short* op = which ? o1 : o0;
            const float* bp = which ? b1 : b0;
#pragma unroll
            for (int r = 0; r < 2; r++)
#pragma unroll
                for (int c = 0; c < 2; c++)
#pragma unroll
                    for (int e = 0; e < 4; e++) {
                        const int m = mw0 + r * 16 + quad * 4 + e;
                        const int n = nn0 + c * 16 + lr;
                        op[(size_t)m * 256 + n] = f2bf(acc[r][c][e] + bp[n]);
                    }
        } else {
#pragma unroll
            for (int r = 0; r < 2; r++)
#pragma unroll
                for (int c = 0; c < 2; c++)
#pragma unroll
                    for (int e = 0; e < 4; e++) {
                        const int m = mw0 + r * 16 + quad * 4 + e;
                        const int nn = nn0 + c * 16 + lr;
                        const int bb_ = m >> 8, j = m & 255, hh = nn >> 5, d = nn & 31;
                        o2[(size_t)((bb_ * 8 + hh) * 32 + d) * 256 + j] = f2bf(acc[r][c][e] + b2[nn]);
                    }
        }
    } else {
#pragma unroll
        for (int r = 0; r < 2; r++)
#pragma unroll
            for (int c = 0; c < 2; c++)
#pragma unroll
                for (int e = 0; e < 4; e++) {
                    const int m = mw0 + r * 16 + quad * 4 + e;
                    const int n = n0 + c * 16 + lr;
                    o0[(size_t)m * 512 + n] = f2bf(fmaxf(acc[r][c][e] + b0[n], 0.f));
                }
    }
}

// bf16 MFMA GEMM: C[M=2048][N] = A[M][K] @ Wt[N][K]^T (+bias, mode epilogue)
// block 128 (2 waves stacked in m), wave tile 32m x 32n; grid (32, N/32).
__global__ __launch_bounds__(128) void gemm_mfma_kernel(
    const unsigned short* __restrict__ A, const unsigned short* __restrict__ Wt,
    const float* __restrict__ b0, const float* __restrict__ b1, const float* __restrict__ b2,
    const float* __restrict__ R, float* __restrict__ outf,
    unsigned short* __restrict__ o0, unsigned short* __restrict__ o1, unsigned short* __restrict__ o2,
    int K, int mode)
{
    const int tid = threadIdx.x;
    const int lane = tid & 63, lr = lane & 15, quad = lane >> 4;
    const int wv = __builtin_amdgcn_readfirstlane((int)(tid >> 6));
    const int m0 = blockIdx.x * 64 + wv * 32;
    const int n0 = blockIdx.y * 32;

    floatx4 acc[2][2];
#pragma unroll
    for (int r = 0; r < 2; r++)
#pragma unroll
        for (int c = 0; c < 2; c++) acc[r][c] = (floatx4){0.f, 0.f, 0.f, 0.f};

    const unsigned short* Ap = A + (size_t)(m0 + lr) * K + quad * 8;
    const unsigned short* Bp = Wt + (size_t)(n0 + lr) * K + quad * 8;
    const int nks = K >> 5;
#pragma unroll 4
    for (int ks = 0; ks < nks; ks++) {
        const int ko = ks * 32;
        bf16x8 a[2], b[2];
#pragma unroll
        for (int r = 0; r < 2; r++) a[r] = *(const bf16x8*)(Ap + (size_t)r * 16 * K + ko);
#pragma unroll
        for (int c = 0; c < 2; c++) b[c] = *(const bf16x8*)(Bp + (size_t)c * 16 * K + ko);
#pragma unroll
        for (int r = 0; r < 2; r++)
#pragma unroll
            for (int c = 0; c < 2; c++)
                acc[r][c] = __builtin_amdgcn_mfma_f32_16x16x32_bf16(a[r], b[c], acc[r][c], 0, 0, 0);
    }

    if (mode == 0) {
        const int which = n0 >> 8, nn0 = n0 & 255;
        if (which < 2) {
            unsigned short* op = which ? o1 : o0;
            const float* bp = which ? b1 : b0;
#pragma unroll
            for (int r = 0; r < 2; r++)
#pragma unroll
                for (int c = 0; c < 2; c++)
#pragma unroll
                    for (int e = 0; e < 4; e++) {
                        const int m = m0 + r * 16 + quad * 4 + e;
                        const int n = nn0 + c * 16 + lr;
                        op[(size_t)m * 256 + n] = f2bf(acc[r][c][e] + bp[n]);
                    }
        } else {
#pragma unroll
            for (int r = 0; r < 2; r++)
#pragma unroll
                for (int c = 0; c < 2; c++)
#pragma unroll
                    for (int e = 0; e < 4; e++) {
                        const int m = m0 + r * 16 + quad * 4 + e;
                        const int nn = nn0 + c * 16 + lr;
                        const int bb_ = m >> 8, j = m & 255, hh = nn >> 5, d = nn & 31;
                        o2[(size_t)((bb_ * 8 + hh) * 32 + d) * 256 + j] = f2bf(acc[r][c][e] + b2[nn]);
                    }
        }
    } else if (mode == 1) {
#pragma unroll
        for (int r = 0; r < 2; r++)
#pragma unroll
            for (int c = 0; c < 2; c++)
#pragma unroll
                for (int e = 0; e < 4; e++) {
                    const int m = m0 + r * 16 + quad * 4 + e;
                    const int n = n0 + c * 16 + lr;
                    outf[(size_t)m * 256 + n] = acc[r][c][e] + b0[n] + R[(size_t)m * 256 + n];
                }
    } else {
#pragma unroll
        for (int r = 0; r < 2; r++)
#pragma unroll
            for (int c = 0; c < 2; c++)
#pragma unroll
                for (int e = 0; e < 4; e++) {
                    const int m = m0 + r * 16 + quad * 4 + e;
                    const int n = n0 + c * 16 + lr;
                    o0[(size_t)m * 512 + n] = f2bf(fmaxf(acc[r][c][e] + b0[n], 0.f));
                }
    }
}

// MFMA attention: grid (4 ic, 8 h, 8 b), block 256 (4 waves, wave = one 16-i tile)
__global__ __launch_bounds__(256) void attn_mfma_kernel(
    const unsigned short* __restrict__ q_bf, const unsigned short* __restrict__ k_bf,
    const unsigned short* __restrict__ vt_bf,
    const float* __restrict__ dist, const unsigned* __restrict__ dmax,
    const float* __restrict__ bw, const float* __restrict__ bb,
    unsigned short* __restrict__ ao_bf)
{
    __shared__ unsigned short Ps[4][16][264];
    const int tid = threadIdx.x;
    const int lane = tid & 63, lr = lane & 15, quad = lane >> 4;
    const int wv = __builtin_amdgcn_readfirstlane((int)(tid >> 6));
    const int ic = blockIdx.x, hh = blockIdx.y, b = blockIdx.z;
    const int i0 = ic * 64 + wv * 16;

    const float dinv = 1.f / (__uint_as_float(*dmax) + 1e-6f);
    const float w0 = bw[0 * 8 + hh], w1 = bw[1 * 8 + hh], w2 = bw[2 * 8 + hh], w3 = bw[3 * 8 + hh];
    const float bbh = bb[hh];
    const float scale = 0.17677669529663687f;

    const bf16x8 aq = *(const bf16x8*)(q_bf + (size_t)(b * 256 + i0 + lr) * 256 + hh * 32 + quad * 8);
    floatx4 sc[16];
#pragma unroll
    for (int c = 0; c < 16; c++) {
        const bf16x8 bk = *(const bf16x8*)(k_bf + (size_t)(b * 256 + c * 16 + lr) * 256 + hh * 32 + quad * 8);
        sc[c] = __builtin_amdgcn_mfma_f32_16x16x32_bf16(aq, bk, (floatx4){0.f, 0.f, 0.f, 0.f}, 0, 0, 0);
    }

#pragma unroll
    for (int e = 0; e < 4; e++) {
        const int i = i0 + quad * 4 + e;
        const float* drow = dist + ((size_t)(b * 256 + i)) * 256;
        float bs[16];
        float mx = -1e30f;
#pragma unroll
        for (int c = 0; c < 16; c++) {
            const int j = c * 16 + lr;
            const float dn = drow[j] * dinv;
            const float rd = fabsf((float)(i - j)) * (1.f / 255.f);
            bs[c] = sc[c][e] * scale + w0 * dn + w1 * rd + w2 * (1.f - rd) + w3 * (1.f - dn) + bbh;
            mx = fmaxf(mx, bs[c]);
        }
        mx = fmaxf(mx, __shfl_xor(mx, 1)); mx = fmaxf(mx, __shfl_xor(mx, 2));
        mx = fmaxf(mx, __shfl_xor(mx, 4)); mx = fmaxf(mx, __shfl_xor(mx, 8));
        float sm = 0.f;
#pragma unroll
        for (int c = 0; c < 16; c++) { bs[c] = __expf(bs[c] - mx); sm += bs[c]; }
        sm += __shfl_xor(sm, 1); sm += __shfl_xor(sm, 2);
        sm += __shfl_xor(sm, 4); sm += __shfl_xor(sm, 8);
        const float rs = 1.f / sm;
#pragma unroll
        for (int c = 0; c < 16; c++)
            Ps[wv][quad * 4 + e][c * 16 + lr] = f2bf(bs[c] * rs);
    }
    __syncthreads();

    floatx4 oc[2];
    oc[0] = (floatx4){0.f, 0.f, 0.f, 0.f};
    oc[1] = (floatx4){0.f, 0.f, 0.f, 0.f};
    const unsigned short* vtb = vt_bf + (size_t)(b * 8 + hh) * 8192;
#pragma unroll
    for (int ks = 0; ks < 8; ks++) {
        const bf16x8 ap = *(const bf16x8*)(&Ps[wv][lr][ks * 32 + quad * 8]);
#pragma unroll
        for (int c2 = 0; c2 < 2; c2++) {
            const bf16x8 bvv = *(const bf16x8*)(vtb + (size_t)(c2 * 16 + lr) * 256 + ks * 32 + quad * 8);
            oc[c2] = __builtin_amdgcn_mfma_f32_16x16x32_bf16(ap, bvv, oc[c2], 0, 0, 0);
        }
    }
#pragma unroll
    for (int c2 = 0; c2 < 2; c2++)
#pragma unroll
        for (int e = 0; e < 4; e++)
            ao_bf[(size_t)(b * 256 + i0 + quad * 4 + e) * 256 + hh * 32 + c2 * 16 + lr] = f2bf(oc[c2][e]);
}

// chunked max-pool over segments + final FC, spread over (b, ns) = 64 blocks;
// partial dot products atomicAdd'ed into out (bias pre-seeded by prep_all).
__global__ __launch_bounds__(256) void pool_fc_kernel(
    const float* __restrict__ h, const float* __restrict__ fcw,
    float* __restrict__ out)
{
    __shared__ float red[8];
    const int b = blockIdx.x, ns = blockIdx.y;
    const int tid = threadIdx.x, lane = tid & 63, wid = tid >> 6;
    const float* hp = h + ((size_t)(b * 256 + ns * 32)) * 256 + tid;
    float m = hp[0];
#pragma unroll
    for (int r = 1; r < 32; r++) m = fmaxf(m, hp[(size_t)r * 256]);
    float a0 = m * fcw[(ns * 256 + tid) * 2 + 0];
    float a1 = m * fcw[(ns * 256 + tid) * 2 + 1];
    a0 = wave_sum(a0);
    a1 = wave_sum(a1);
    if (lane == 0) { red[wid] = a0; red[4 + wid] = a1; }
    __syncthreads();
    if (tid == 0) atomicAdd(&out[b * 2 + 0], red[0] + red[1] + red[2] + red[3]);
    if (tid == 1) atomicAdd(&out[b * 2 + 1], red[4] + red[5] + red[6] + red[7]);
}

extern "C" void kernel_launch(void* const* d_in, const int* in_sizes, int n_in,
                              void* d_out, int out_size, void* d_ws, size_t ws_size,
                              hipStream_t stream)
{
    (void)in_sizes; (void)n_in; (void)out_size; (void)ws_size;
    const float* x       = (const float*)d_in[0];
    const float* conv1_w = (const float*)d_in[1];
    const float* conv1_b = (const float*)d_in[2];
    const float* conv2_w = (const float*)d_in[3];
    const float* conv2_b = (const float*)d_in[4];
    const float* ln1_g   = (const float*)d_in[5];
    const float* ln1_b   = (const float*)d_in[6];
    const float* wq = (const float*)d_in[7];  const float* bq = (const float*)d_in[8];
    const float* wk = (const float*)d_in[9];  const float* bk = (const float*)d_in[10];
    const float* wvp = (const float*)d_in[11]; const float* bv = (const float*)d_in[12];
    const float* wo = (const float*)d_in[13]; const float* bo = (const float*)d_in[14];
    const float* bias_w = (const float*)d_in[15];
    const float* bias_b = (const float*)d_in[16];
    const float* ln2_g  = (const float*)d_in[17];
    const float* ln2_b  = (const float*)d_in[18];
    const float* ffn_w1 = (const float*)d_in[19]; const float* ffn_b1 = (const float*)d_in[20];
    const float* ffn_w2 = (const float*)d_in[21]; const float* ffn_b2 = (const float*)d_in[22];
    const float* fc_w   = (const float*)d_in[23]; const float* fc_b = (const float*)d_in[24];
    float* out = (float*)d_out;

    float* ws = (float*)d_ws;
    float* h    = ws;                         // [2048,256] fp32
    float* dist = h + 524288;                 // [8,256,256] fp32
    float* sqv  = dist + 524288;              // [2048]
    unsigned* dmax = (unsigned*)(sqv + 2048);
    unsigned* cnnmax = (unsigned*)(sqv + 2048 + 16);              // [2048,256]
    unsigned short* hn_bf = (unsigned short*)(sqv + 2048 + 16 + 524288);  // [2048,256] (unused)
    unsigned short* q_bf  = hn_bf + 524288;
    unsigned short* k_bf  = q_bf + 524288;
    unsigned short* vt_bf = k_bf + 524288;    // [8,8,32,256] = [b,h,d,j]
    unsigned short* ao_bf = vt_bf + 524288;   // [2048,256]
    unsigned short* fm_bf = ao_bf + 524288;   // [2048,512]
    unsigned short* wtb   = fm_bf + 1048576;  // [2][524288]
    unsigned short* w2b   = wtb + 1048576;    // 256*12*8192 bf16 = 50.3 MB

    prep_all_kernel<<<6144, 256, 0, stream>>>(
        dmax, cnnmax, wq, wk, wvp, wo, ffn_w1, ffn_w2, wtb, conv2_w, w2b,
        fc_b, out);
    conv2_fused_kernel<<<4096, 512, 0, stream>>>(
        w2b, x, conv1_w, conv1_b, conv2_b, cnnmax);
    ln0_kernel<<<512, 256, 0, stream>>>(cnnmax, h, sqv);
    dist_kernel<<<1024, 256, 0, stream>>>(h, sqv, dist, dmax);

    for (int l = 0; l < 2; l++) {
        const unsigned short* wqkvT = wtb + (size_t)l * 524288;
        const unsigned short* woT   = wqkvT + 196608;
        const unsigned short* f1T   = wqkvT + 262144;
        const unsigned short* f2T   = wqkvT + 393216;

        gemm_ln_kernel<<<dim3(32, 24), 128, 0, stream>>>(
            h, wqkvT, ln1_g + l * 256, ln1_b + l * 256,
            bq + l * 256, bk + l * 256, bv + l * 256,
            q_bf, k_bf, vt_bf, 0);
        attn_mfma_kernel<<<dim3(4, 8, 8), 256, 0, stream>>>(
            q_bf, k_bf, vt_bf, dist, dmax, bias_w + l * 32, bias_b + l * 8, ao_bf);
        gemm_mfma_kernel<<<dim3(32, 8), 128, 0, stream>>>(
            ao_bf, woT, bo + l * 256, nullptr, nullptr,
            h, h, nullptr, nullptr, nullptr, 256, 1);
        gemm_ln_kernel<<<dim3(32, 16), 128, 0, stream>>>(
            h, f1T, ln2_g + l * 256, ln2_b + l * 256,
            ffn_b1 + l * 512, nullptr, nullptr,
            fm_bf, nullptr, nullptr, 2);
        gemm_mfma_kernel<<<dim3(32, 8), 128, 0, stream>>>(
            fm_bf, f2T, ffn_b2 + l * 256, nullptr, nullptr,
            h, h, nullptr, nullptr, nullptr, 512, 1);
    }
    pool_fc_kernel<<<dim3(8, 8), 256, 0, stream>>>(h, fc_w, out);
}